// Round 11
// baseline (295.141 us; speedup 1.0000x reference)
//
#include <hip/hip_runtime.h>
#include <math.h>

typedef __attribute__((ext_vector_type(8))) short short8;
typedef __attribute__((ext_vector_type(4))) float floatx4;

__device__ __forceinline__ void load_lds16(const void* g, void* l) {
    __builtin_amdgcn_global_load_lds((const __attribute__((address_space(1))) void*)g,
                                     (__attribute__((address_space(3))) void*)l,
                                     16, 0, 0);
}

__device__ __forceinline__ unsigned short f2bf(float x) {
    union { float f; unsigned int u; } v; v.f = x;
    unsigned int r = v.u + 0x7fffu + ((v.u >> 16) & 1u);
    return (unsigned short)(r >> 16);
}

// pack two fp32 -> two bf16 (round-half-up) in one v_perm_b32
__device__ __forceinline__ unsigned int pack_bf(float f0, float f1) {
    union { float f; unsigned int u; } a, b;
    a.f = f0; b.f = f1;
    return __builtin_amdgcn_perm(b.u + 0x8000u, a.u + 0x8000u, 0x07060302u);
}

__device__ __forceinline__ float fast_exp2(float x) {
#if __has_builtin(__builtin_amdgcn_exp2f)
    return __builtin_amdgcn_exp2f(x);
#else
    return __expf(x * 0.69314718056f);
#endif
}

__device__ __forceinline__ float fast_rcp(float x) {
#if __has_builtin(__builtin_amdgcn_rcpf)
    return __builtin_amdgcn_rcpf(x);
#else
    return 1.0f / x;
#endif
}

#define NEG_LOG2E (-1.4426950408889634f)

// ---- prep: weights + Toeplitz XW -> bf16 in MFMA-A-fragment order ----
// blocks: [0,512) w0 | [512,6656) w | [6656,7680) wf-pad | [7680,7936) XW-frag
// XW-frag record (nblk, r): 64 lanes x 8 bf16; lane l holds
// XW[nblk*16 + (l&15)][r*32 + (l>>4)*8 + e], e=0..7  (same layout as weights,
// proven by fused_mlp's load_w -> mfma path). XW[n][k] = (j<65)? xi[m][n+j] : 0
// with m = k/68, j = k%68.
__global__ void prep(const float* __restrict__ w0, const float* __restrict__ w,
                     const float* __restrict__ wf, const float* __restrict__ xi,
                     unsigned short* __restrict__ w0d, unsigned short* __restrict__ wd,
                     unsigned short* __restrict__ wfd, unsigned short* __restrict__ xwf) {
    const int bid = blockIdx.x;
    if (bid < 6656) {
        const bool is0 = bid < 512;
        const int c = (is0 ? bid : bid - 512) * 256 + threadIdx.x;
        const int cpm = is0 ? 2048 : 8192;
        const int Kk  = is0 ? 2 : 8;
        const int K   = Kk * 32;
        const int mm  = c / cpm;
        const int cm  = c - mm * cpm;
        const int rblk = cm / (Kk * 64);
        const int rem  = cm - rblk * (Kk * 64);
        const int kk   = rem >> 6;
        const int lane = rem & 63;
        const int r  = rblk * 16 + (lane & 15);
        const int k0 = kk * 32 + (lane >> 4) * 8;
        const float* srcp = (is0 ? w0 : w) + ((size_t)mm * 256 + r) * K + k0;
        unsigned short* dstp = (is0 ? w0d : wd) + (size_t)c * 8;
        float4 a = *(const float4*)srcp;
        float4 b = *(const float4*)(srcp + 4);
        short8 o = { (short)f2bf(a.x), (short)f2bf(a.y), (short)f2bf(a.z), (short)f2bf(a.w),
                     (short)f2bf(b.x), (short)f2bf(b.y), (short)f2bf(b.z), (short)f2bf(b.w) };
        *(short8*)dstp = o;
    } else if (bid < 7680) {
        const int c = (bid - 6656) * 256 + threadIdx.x;
        const int m  = c >> 12;
        const int cm = c & 4095;
        const int rblk = cm >> 9;
        const int rem  = cm & 511;
        const int kk   = rem >> 6;
        const int lane = rem & 63;
        const int r  = rblk * 16 + (lane & 15);
        const int k0 = kk * 32 + (lane >> 4) * 8;
        short8 o = {0,0,0,0,0,0,0,0};
        if (r < 65) {
            const float* srcp = wf + ((size_t)m * 65 + r) * 256 + k0;
            float4 a = *(const float4*)srcp;
            float4 b = *(const float4*)(srcp + 4);
            o = (short8){ (short)f2bf(a.x), (short)f2bf(a.y), (short)f2bf(a.z), (short)f2bf(a.w),
                          (short)f2bf(b.x), (short)f2bf(b.y), (short)f2bf(b.z), (short)f2bf(b.w) };
        }
        *(short8*)(wfd + (size_t)c * 8) = o;
    } else {
        // XW fragment build: one block per nblk (16 n-rows), 136 records of 1 KB
        const int nblk = bid - 7680;
        const int lane = threadIdx.x & 63, wv = threadIdx.x >> 6;
        const int n = (nblk << 4) + (lane & 15);
        const int koff = (lane >> 4) << 3;
        unsigned short* dst = xwf + ((size_t)nblk * 136 * 64 + lane) * 8;
        for (int r = wv; r < 136; r += 4) {
            const int k0 = r * 32 + koff;
            short8 o;
            #pragma unroll
            for (int e = 0; e < 8; ++e) {
                const int k = k0 + e;
                const int m = k / 68;          // magic-mul div
                const int j = k - m * 68;
                o[e] = (j < 65) ? (short)f2bf(xi[(size_t)m * 4160 + n + j]) : (short)0;
            }
            *(short8*)(dst + (size_t)r * 512) = o;
        }
    }
}

// ---- weight fragments -> registers, once per layer (amortized over 2 sub-tiles) ----
template<int K, int I>
__device__ __forceinline__ void load_w(
    const unsigned short* __restrict__ Wt, int wave, int lane, short8 (&w)[I][K / 32])
{
    constexpr int Kk = K / 32;
    const unsigned short* wb = Wt + ((size_t)(wave * I * Kk) * 64 + lane) * 8;
    #pragma unroll
    for (int i = 0; i < I; ++i)
        #pragma unroll
        for (int kk = 0; kk < Kk; ++kk)
            w[i][kk] = *(const short8*)(wb + (size_t)(i * Kk + kk) * 512);
}

// ---- MFMA sweep over one 64-col sub-tile t, weights from registers ----
// X layout: X[b][k] at b*K + ((k/8) ^ (b&7))*8 + (k&7)   (shorts)
template<int K, int I>
__device__ __forceinline__ void mfma_tile(
    const short8 (&w)[I][K / 32], const unsigned short* src, int t,
    int quad, int l16, floatx4 (&acc)[I][4])
{
    constexpr int Kk = K / 32;
    #pragma unroll
    for (int i = 0; i < I; ++i)
        #pragma unroll
        for (int j = 0; j < 4; ++j) acc[i][j] = (floatx4){0.f, 0.f, 0.f, 0.f};
    #pragma unroll
    for (int kk = 0; kk < Kk; ++kk) {
        short8 bf[4];
        #pragma unroll
        for (int j = 0; j < 4; ++j) {
            const int cb = t * 64 + j * 16 + l16;
            bf[j] = *(const short8*)&src[cb * K + (((kk * 4 + quad) ^ (cb & 7)) * 8)];
        }
        #pragma unroll
        for (int i = 0; i < I; ++i)
            #pragma unroll
            for (int j = 0; j < 4; ++j)
                acc[i][j] = __builtin_amdgcn_mfma_f32_16x16x32_bf16(w[i][kk], bf[j], acc[i][j], 0, 0, 0);
    }
}

// epilogue for sub-tile t: fused bias+sigmoid, perm pack, in-place K_out=256 layout
template<int I>
__device__ __forceinline__ void mlp_write_t(
    const float* __restrict__ bm, unsigned short* dst, int t,
    int wave, int quad, int l16, floatx4 (&acc)[I][4])
{
    const int rbw = wave * (I * 16);
    #pragma unroll
    for (int i = 0; i < I; ++i) {
        const int rb = rbw + i * 16 + quad * 4;
        float c0 = bm[rb]     * NEG_LOG2E;
        float c1 = bm[rb + 1] * NEG_LOG2E;
        float c2 = bm[rb + 2] * NEG_LOG2E;
        float c3 = bm[rb + 3] * NEG_LOG2E;
        #pragma unroll
        for (int j = 0; j < 4; ++j) {
            const int cb = t * 64 + j * 16 + l16;
            float r0 = fast_rcp(1.0f + fast_exp2(fmaf(acc[i][j][0], NEG_LOG2E, c0)));
            float r1 = fast_rcp(1.0f + fast_exp2(fmaf(acc[i][j][1], NEG_LOG2E, c1)));
            float r2 = fast_rcp(1.0f + fast_exp2(fmaf(acc[i][j][2], NEG_LOG2E, c2)));
            float r3 = fast_rcp(1.0f + fast_exp2(fmaf(acc[i][j][3], NEG_LOG2E, c3)));
            uint2 o = { pack_bf(r0, r1), pack_bf(r2, r3) };
            *(uint2*)&dst[cb * 256 + (((rb >> 3) ^ (cb & 7)) * 8) + (rb & 7)] = o;
        }
    }
}

// ---- fused MLP, weight-register-resident (R5 version — best measured, 49.8 us) ----
__global__ __launch_bounds__(256, 2)
void fused_mlp(const float* __restrict__ u,
               const unsigned short* __restrict__ w0_bf, const float* __restrict__ b0_,
               const unsigned short* __restrict__ w_bf,  const float* __restrict__ b_,
               const unsigned short* __restrict__ wf_bf, const float* __restrict__ bf_,
               unsigned short* __restrict__ Gflat) {
    __shared__ unsigned short X[128 * 256];   // 64 KB

    const int bid = blockIdx.x;
    const int xcd = bid & 7, slot = bid >> 3;           // slot 0..63
    const int m  = (xcd << 3) + (slot >> 3);            // 8 m per XCD
    const int b0 = (slot & 7) << 7;                     // 8 batch-tiles of 128
    const int tid = threadIdx.x, wave = tid >> 6, lane = tid & 63;
    const int quad = lane >> 4, l16 = lane & 15;

    // stage u (fp32) -> X (bf16, K=64 layout), perm-packed
    {
        const int b = tid >> 1, hk = tid & 1;
        const float* up = u + (size_t)(b0 + b) * 64 + hk * 32;
        #pragma unroll
        for (int c = 0; c < 4; ++c) {
            float4 v0 = *(const float4*)(up + c * 8);
            float4 v1 = *(const float4*)(up + c * 8 + 4);
            uint4 p = { pack_bf(v0.x, v0.y), pack_bf(v0.z, v0.w),
                        pack_bf(v1.x, v1.y), pack_bf(v1.z, v1.w) };
            *(uint4*)&X[b * 64 + (((hk * 4 + c) ^ (b & 7)) * 8)] = p;
        }
    }
    __syncthreads();

    floatx4 acc[4][4];

    // ---- layer 0 (K=64): both sub-tiles computed before any write ----
    {
        short8 w0r[4][2];
        load_w<64, 4>(w0_bf + (size_t)m * 16384, wave, lane, w0r);
        floatx4 acc2[4][4];
        mfma_tile<64, 4>(w0r, X, 0, quad, l16, acc);
        mfma_tile<64, 4>(w0r, X, 1, quad, l16, acc2);
        __syncthreads();
        mlp_write_t<4>(b0_ + (size_t)m * 256, X, 0, wave, quad, l16, acc);
        mlp_write_t<4>(b0_ + (size_t)m * 256, X, 1, wave, quad, l16, acc2);
        __syncthreads();
    }

    // ---- main layers (K=256): weights in regs, 2 sub-tiles, 2 barriers/layer ----
    #pragma unroll 1
    for (int l = 0; l < 3; ++l) {
        short8 wr[4][8];
        load_w<256, 4>(w_bf + ((size_t)l * 64 + m) * 65536, wave, lane, wr);
        const float* bm = b_ + ((size_t)l * 64 + m) * 256;
        mfma_tile<256, 4>(wr, X, 0, quad, l16, acc);
        __syncthreads();
        mlp_write_t<4>(bm, X, 0, wave, quad, l16, acc);
        mfma_tile<256, 4>(wr, X, 1, quad, l16, acc);
        __syncthreads();
        mlp_write_t<4>(bm, X, 1, wave, quad, l16, acc);
    }
    __syncthreads();   // all w(1) writes visible before final layer reads tile 1

    // ---- final layer (K=256, 68 padded rows): direct global G write ----
    {
        short8 wfr[2][8];
        load_w<256, 2>(wf_bf + (size_t)m * 32768, wave, lane, wfr);
        const float* bm = bf_ + (size_t)m * 65;
        unsigned short* Gg = Gflat + (size_t)b0 * 4352 + m * 68;
        floatx4 acf[2][4];
        #pragma unroll
        for (int t = 0; t < 2; ++t) {
            mfma_tile<256, 2>(wfr, X, t, quad, l16, acf);
            #pragma unroll
            for (int i = 0; i < 2; ++i) {
                const int rb = wave * 32 + i * 16 + quad * 4;
                if (rb < 68) {
                    float c[4];
                    #pragma unroll
                    for (int rr = 0; rr < 4; ++rr)
                        c[rr] = (rb + rr < 65) ? bm[rb + rr] * NEG_LOG2E : 0.0f;
                    #pragma unroll
                    for (int j = 0; j < 4; ++j) {
                        const int cb = t * 64 + j * 16 + l16;
                        float r0 = fast_rcp(1.0f + fast_exp2(fmaf(acf[i][j][0], NEG_LOG2E, c[0])));
                        float r1 = fast_rcp(1.0f + fast_exp2(fmaf(acf[i][j][1], NEG_LOG2E, c[1])));
                        float r2 = fast_rcp(1.0f + fast_exp2(fmaf(acf[i][j][2], NEG_LOG2E, c[2])));
                        float r3 = fast_rcp(1.0f + fast_exp2(fmaf(acf[i][j][3], NEG_LOG2E, c[3])));
                        uint2 o = { pack_bf(r0, r1), pack_bf(r2, r3) };
                        *(uint2*)&Gg[(size_t)cb * 4352 + rb] = o;
                    }
                }
            }
        }
    }
}

// ---- contract helpers (R11) ----
__device__ __forceinline__ void stage_b(
    const unsigned short* __restrict__ G, unsigned short* Bsb,
    int c0, int k0, int wave, int lrow, int spos)
{
    #pragma unroll
    for (int t = 0; t < 4; ++t) {
        const int row = wave * 32 + t * 8 + lrow;
        const int fc  = spos ^ (row & 7);
        load_lds16(G + (size_t)(c0 + row) * 4352 + k0 + fc * 8,
                   Bsb + (wave * 32 + t * 8) * 64);
    }
}

__device__ __forceinline__ void load_a(
    const unsigned short* __restrict__ Abase, int kt, short8 (&af)[8])
{
    #pragma unroll
    for (int i = 0; i < 4; ++i)
        #pragma unroll
        for (int kk = 0; kk < 2; ++kk)
            af[kk * 4 + i] = *(const short8*)(Abase + (size_t)(i * 136 + kt * 2 + kk) * 512);
}

__device__ __forceinline__ void comp_frag(
    const short8 (&af)[8], const unsigned short* Bsb,
    int wc, int quad, int l16, floatx4 (&acc)[4][4])
{
    #pragma unroll
    for (int kk = 0; kk < 2; ++kk) {
        short8 bfr[4];
        #pragma unroll
        for (int j = 0; j < 4; ++j) {
            const int cb = wc + j * 16 + l16;
            bfr[j] = *(const short8*)&Bsb[cb * 64 + (((kk * 4 + quad) ^ (cb & 7)) * 8)];
        }
        #pragma unroll
        for (int i = 0; i < 4; ++i)
            #pragma unroll
            for (int j = 0; j < 4; ++j)
                acc[i][j] = __builtin_amdgcn_mfma_f32_16x16x32_bf16(af[kk * 4 + i], bfr[j], acc[i][j], 0, 0, 0);
    }
}

// ---- contraction: FULL-K, 128x128, A fragment-direct from L2 (R11) ----
// grid 256 = 32 n-tiles x 8 b-tiles, 1 block/CU, 68 K-iters, fp32 direct out.
// R10 lesson: 2-phase stall removal is neutral; the cost was LDS-read volume
// (96 b128/CU-iter). Here A comes straight from the prep-fragmented XWf
// (8 coalesced 1KB loads/iter/wave, prefetched 1 K-tile ahead -> L2 latency
// hides under the 621-cy MFMA phase); only B (G) staged in LDS (dbuf).
// LDS reads 96 -> 32 per CU-iter -> MFMA-bound (floor 17.6 us). XCD-colocated
// n keeps the 4.5 MB XWf slice ~L2-resident.
__global__ __launch_bounds__(256, 1)
void contract_gemm(const unsigned short* __restrict__ XWf,
                   const unsigned short* __restrict__ G,
                   float* __restrict__ out) {
    const int bid = blockIdx.x;
    const int xcd = bid & 7, slot = bid >> 3;           // 0..31
    const int r0 = ((xcd << 2) + (slot >> 3)) << 7;     // 32 n-tiles, 4/XCD
    const int c0 = (slot & 7) << 7;                     // 8 b-tiles of 128

    __shared__ unsigned short Bs[2][128 * 64];          // 2 x 16 KB

    const int tid = threadIdx.x;
    const int wave = tid >> 6, lane = tid & 63;
    const int quad = lane >> 4, l16 = lane & 15;
    const int wr = (wave & 1) * 64;                     // wave n-offset
    const int wc = (wave >> 1) * 64;                    // wave b-offset
    const int lrow = lane >> 3, spos = lane & 7;

    const unsigned short* Abase =
        XWf + ((size_t)(((r0 + wr) >> 4) * 136) * 64 + lane) * 8;

    floatx4 acc[4][4];
    #pragma unroll
    for (int i = 0; i < 4; ++i)
        #pragma unroll
        for (int j = 0; j < 4; ++j) acc[i][j] = (floatx4){0.f, 0.f, 0.f, 0.f};

    short8 afA[8], afB[8];

    // prologue: stage B k-tile 0, load A k-tile 0
    stage_b(G, Bs[0], c0, 0, wave, lrow, spos);
    load_a(Abase, 0, afA);
    __syncthreads();

    for (int t = 0; t < 68; t += 2) {
        // iter t: prefetch t+1 (B->buf1, A->afB), compute buf0/afA
        stage_b(G, Bs[1], c0, (t + 1) * 64, wave, lrow, spos);
        load_a(Abase, t + 1, afB);
        comp_frag(afA, Bs[0], wc, quad, l16, acc);
        __syncthreads();
        // iter t+1: prefetch t+2 (B->buf0, A->afA), compute buf1/afB
        if (t + 2 < 68) {
            stage_b(G, Bs[0], c0, (t + 2) * 64, wave, lrow, spos);
            load_a(Abase, t + 2, afA);
        }
        comp_frag(afB, Bs[1], wc, quad, l16, acc);
        __syncthreads();
    }

    #pragma unroll
    for (int i = 0; i < 4; ++i) {
        const int rb = r0 + wr + i * 16 + quad * 4;
        #pragma unroll
        for (int rr = 0; rr < 4; ++rr)
            #pragma unroll
            for (int j = 0; j < 4; ++j) {
                const int col = c0 + wc + j * 16 + l16;
                out[(size_t)(rb + rr) * 1024 + col] = acc[i][j][rr];
            }
    }
}

extern "C" void kernel_launch(void* const* d_in, const int* in_sizes, int n_in,
                              void* d_out, int out_size, void* d_ws, size_t ws_size,
                              hipStream_t stream) {
    const float* u   = (const float*)d_in[0];
    const float* w0  = (const float*)d_in[1];
    const float* b0_ = (const float*)d_in[2];
    const float* w   = (const float*)d_in[3];
    const float* b   = (const float*)d_in[4];
    const float* wf  = (const float*)d_in[5];
    const float* bf_ = (const float*)d_in[6];
    const float* xi  = (const float*)d_in[7];
    float* out = (float*)d_out;

    unsigned short* w0_bf = (unsigned short*)d_ws;             // 1,048,576
    unsigned short* w_bf  = w0_bf + 1048576;                   // 12,582,912
    unsigned short* wf_bf = w_bf  + 12582912;                  // 2,097,152
    unsigned short* Gflat = wf_bf + 2097152;                   // 4,456,448 (1024 x 4352)
    unsigned short* XWf   = Gflat + 4456448;                   // 17,825,792 (256 nblk x 136 x 512)

    prep<<<7936, 256, 0, stream>>>(w0, w, wf, xi, w0_bf, w_bf, wf_bf, XWf);
    fused_mlp<<<512, 256, 0, stream>>>(u, w0_bf, b0_, w_bf, b, wf_bf, bf_, Gflat);
    contract_gemm<<<256, 256, 0, stream>>>(XWf, Gflat, out);
}

// Round 13
// 263.824 us; speedup vs baseline: 1.1187x; 1.1187x over previous
//
#include <hip/hip_runtime.h>
#include <math.h>

typedef __attribute__((ext_vector_type(8))) short short8;
typedef __attribute__((ext_vector_type(4))) float floatx4;

__device__ __forceinline__ void load_lds16(const void* g, void* l) {
    __builtin_amdgcn_global_load_lds((const __attribute__((address_space(1))) void*)g,
                                     (__attribute__((address_space(3))) void*)l,
                                     16, 0, 0);
}

__device__ __forceinline__ unsigned short f2bf(float x) {
    union { float f; unsigned int u; } v; v.f = x;
    unsigned int r = v.u + 0x7fffu + ((v.u >> 16) & 1u);
    return (unsigned short)(r >> 16);
}

// pack two fp32 -> two bf16 (round-half-up) in one v_perm_b32
__device__ __forceinline__ unsigned int pack_bf(float f0, float f1) {
    union { float f; unsigned int u; } a, b;
    a.f = f0; b.f = f1;
    return __builtin_amdgcn_perm(b.u + 0x8000u, a.u + 0x8000u, 0x07060302u);
}

__device__ __forceinline__ float fast_exp2(float x) {
#if __has_builtin(__builtin_amdgcn_exp2f)
    return __builtin_amdgcn_exp2f(x);
#else
    return __expf(x * 0.69314718056f);
#endif
}

__device__ __forceinline__ float fast_rcp(float x) {
#if __has_builtin(__builtin_amdgcn_rcpf)
    return __builtin_amdgcn_rcpf(x);
#else
    return 1.0f / x;
#endif
}

#define NEG_LOG2E (-1.4426950408889634f)

// ---- prep: weights + Toeplitz XW -> bf16 in MFMA-A-fragment order ----
// blocks: [0,512) w0 | [512,6656) w | [6656,7680) wf-pad | [7680,12032) XW-frag
// XW-frag record (nblk, r): 64 lanes x 8 bf16; lane l holds
// XW[nblk*16 + (l&15)][r*32 + (l>>4)*8 + e], e=0..7. XW[n][k] = (j<65)?
// xi[m][n+j] : 0 with m=k/68, j=k%68. R11 lesson: 256-block build was a
// latency tail (95 us, VALUBusy 10) -> spread over 4352 blocks (17/nblk).
__global__ void prep(const float* __restrict__ w0, const float* __restrict__ w,
                     const float* __restrict__ wf, const float* __restrict__ xi,
                     unsigned short* __restrict__ w0d, unsigned short* __restrict__ wd,
                     unsigned short* __restrict__ wfd, unsigned short* __restrict__ xwf) {
    const int bid = blockIdx.x;
    if (bid < 6656) {
        const bool is0 = bid < 512;
        const int c = (is0 ? bid : bid - 512) * 256 + threadIdx.x;
        const int cpm = is0 ? 2048 : 8192;
        const int Kk  = is0 ? 2 : 8;
        const int K   = Kk * 32;
        const int mm  = c / cpm;
        const int cm  = c - mm * cpm;
        const int rblk = cm / (Kk * 64);
        const int rem  = cm - rblk * (Kk * 64);
        const int kk   = rem >> 6;
        const int lane = rem & 63;
        const int r  = rblk * 16 + (lane & 15);
        const int k0 = kk * 32 + (lane >> 4) * 8;
        const float* srcp = (is0 ? w0 : w) + ((size_t)mm * 256 + r) * K + k0;
        unsigned short* dstp = (is0 ? w0d : wd) + (size_t)c * 8;
        float4 a = *(const float4*)srcp;
        float4 b = *(const float4*)(srcp + 4);
        short8 o = { (short)f2bf(a.x), (short)f2bf(a.y), (short)f2bf(a.z), (short)f2bf(a.w),
                     (short)f2bf(b.x), (short)f2bf(b.y), (short)f2bf(b.z), (short)f2bf(b.w) };
        *(short8*)dstp = o;
    } else if (bid < 7680) {
        const int c = (bid - 6656) * 256 + threadIdx.x;
        const int m  = c >> 12;
        const int cm = c & 4095;
        const int rblk = cm >> 9;
        const int rem  = cm & 511;
        const int kk   = rem >> 6;
        const int lane = rem & 63;
        const int r  = rblk * 16 + (lane & 15);
        const int k0 = kk * 32 + (lane >> 4) * 8;
        short8 o = {0,0,0,0,0,0,0,0};
        if (r < 65) {
            const float* srcp = wf + ((size_t)m * 65 + r) * 256 + k0;
            float4 a = *(const float4*)srcp;
            float4 b = *(const float4*)(srcp + 4);
            o = (short8){ (short)f2bf(a.x), (short)f2bf(a.y), (short)f2bf(a.z), (short)f2bf(a.w),
                          (short)f2bf(b.x), (short)f2bf(b.y), (short)f2bf(b.z), (short)f2bf(b.w) };
        }
        *(short8*)(wfd + (size_t)c * 8) = o;
    } else {
        // XW fragment build: 4352 blocks = 256 nblk x 17 rchunks of 8 records
        const int idx  = bid - 7680;
        const int nblk = idx / 17;
        const int rc   = idx - nblk * 17;
        const int lane = threadIdx.x & 63, wv = threadIdx.x >> 6;
        const int n    = (nblk << 4) + (lane & 15);
        const int koff = (lane >> 4) << 3;
        unsigned short* dst = xwf + (size_t)(nblk * 136) * 512 + lane * 8;
        #pragma unroll
        for (int rr = 0; rr < 2; ++rr) {
            const int r  = rc * 8 + wv * 2 + rr;
            const int k0 = r * 32 + koff;
            short8 o;
            #pragma unroll
            for (int e = 0; e < 8; ++e) {
                const int k = k0 + e;
                const int m = k / 68;
                const int j = k - m * 68;
                o[e] = (j < 65) ? (short)f2bf(xi[(size_t)m * 4160 + n + j]) : (short)0;
            }
            *(short8*)(dst + (size_t)r * 512) = o;
        }
    }
}

// ---- weight fragments -> registers, once per layer ----
template<int K, int I>
__device__ __forceinline__ void load_w(
    const unsigned short* __restrict__ Wt, int wave, int lane, short8 (&w)[I][K / 32])
{
    constexpr int Kk = K / 32;
    const unsigned short* wb = Wt + ((size_t)(wave * I * Kk) * 64 + lane) * 8;
    #pragma unroll
    for (int i = 0; i < I; ++i)
        #pragma unroll
        for (int kk = 0; kk < Kk; ++kk)
            w[i][kk] = *(const short8*)(wb + (size_t)(i * Kk + kk) * 512);
}

// ---- MFMA sweep over one 64-col sub-tile t, weights from registers ----
// X layout: X[b][k] at b*K + ((k/8) ^ (b&7))*8 + (k&7)   (shorts)
template<int K, int I>
__device__ __forceinline__ void mfma_tile(
    const short8 (&w)[I][K / 32], const unsigned short* src, int t,
    int quad, int l16, floatx4 (&acc)[I][4])
{
    constexpr int Kk = K / 32;
    #pragma unroll
    for (int i = 0; i < I; ++i)
        #pragma unroll
        for (int j = 0; j < 4; ++j) acc[i][j] = (floatx4){0.f, 0.f, 0.f, 0.f};
    #pragma unroll
    for (int kk = 0; kk < Kk; ++kk) {
        short8 bf[4];
        #pragma unroll
        for (int j = 0; j < 4; ++j) {
            const int cb = t * 64 + j * 16 + l16;
            bf[j] = *(const short8*)&src[cb * K + (((kk * 4 + quad) ^ (cb & 7)) * 8)];
        }
        #pragma unroll
        for (int i = 0; i < I; ++i)
            #pragma unroll
            for (int j = 0; j < 4; ++j)
                acc[i][j] = __builtin_amdgcn_mfma_f32_16x16x32_bf16(w[i][kk], bf[j], acc[i][j], 0, 0, 0);
    }
}

// epilogue for sub-tile t: fused bias+sigmoid, perm pack, in-place K_out=256 layout
template<int I>
__device__ __forceinline__ void mlp_write_t(
    const float* __restrict__ bm, unsigned short* dst, int t,
    int wave, int quad, int l16, floatx4 (&acc)[I][4])
{
    const int rbw = wave * (I * 16);
    #pragma unroll
    for (int i = 0; i < I; ++i) {
        const int rb = rbw + i * 16 + quad * 4;
        float c0 = bm[rb]     * NEG_LOG2E;
        float c1 = bm[rb + 1] * NEG_LOG2E;
        float c2 = bm[rb + 2] * NEG_LOG2E;
        float c3 = bm[rb + 3] * NEG_LOG2E;
        #pragma unroll
        for (int j = 0; j < 4; ++j) {
            const int cb = t * 64 + j * 16 + l16;
            float r0 = fast_rcp(1.0f + fast_exp2(fmaf(acc[i][j][0], NEG_LOG2E, c0)));
            float r1 = fast_rcp(1.0f + fast_exp2(fmaf(acc[i][j][1], NEG_LOG2E, c1)));
            float r2 = fast_rcp(1.0f + fast_exp2(fmaf(acc[i][j][2], NEG_LOG2E, c2)));
            float r3 = fast_rcp(1.0f + fast_exp2(fmaf(acc[i][j][3], NEG_LOG2E, c3)));
            uint2 o = { pack_bf(r0, r1), pack_bf(r2, r3) };
            *(uint2*)&dst[cb * 256 + (((rb >> 3) ^ (cb & 7)) * 8) + (rb & 7)] = o;
        }
    }
}

// ---- fused MLP, weight-register-resident (R5 version — best measured, 49.8 us) ----
__global__ __launch_bounds__(256, 2)
void fused_mlp(const float* __restrict__ u,
               const unsigned short* __restrict__ w0_bf, const float* __restrict__ b0_,
               const unsigned short* __restrict__ w_bf,  const float* __restrict__ b_,
               const unsigned short* __restrict__ wf_bf, const float* __restrict__ bf_,
               unsigned short* __restrict__ Gflat) {
    __shared__ unsigned short X[128 * 256];   // 64 KB

    const int bid = blockIdx.x;
    const int xcd = bid & 7, slot = bid >> 3;           // slot 0..63
    const int m  = (xcd << 3) + (slot >> 3);            // 8 m per XCD
    const int b0 = (slot & 7) << 7;                     // 8 batch-tiles of 128
    const int tid = threadIdx.x, wave = tid >> 6, lane = tid & 63;
    const int quad = lane >> 4, l16 = lane & 15;

    // stage u (fp32) -> X (bf16, K=64 layout), perm-packed
    {
        const int b = tid >> 1, hk = tid & 1;
        const float* up = u + (size_t)(b0 + b) * 64 + hk * 32;
        #pragma unroll
        for (int c = 0; c < 4; ++c) {
            float4 v0 = *(const float4*)(up + c * 8);
            float4 v1 = *(const float4*)(up + c * 8 + 4);
            uint4 p = { pack_bf(v0.x, v0.y), pack_bf(v0.z, v0.w),
                        pack_bf(v1.x, v1.y), pack_bf(v1.z, v1.w) };
            *(uint4*)&X[b * 64 + (((hk * 4 + c) ^ (b & 7)) * 8)] = p;
        }
    }
    __syncthreads();

    floatx4 acc[4][4];

    // ---- layer 0 (K=64): both sub-tiles computed before any write ----
    {
        short8 w0r[4][2];
        load_w<64, 4>(w0_bf + (size_t)m * 16384, wave, lane, w0r);
        floatx4 acc2[4][4];
        mfma_tile<64, 4>(w0r, X, 0, quad, l16, acc);
        mfma_tile<64, 4>(w0r, X, 1, quad, l16, acc2);
        __syncthreads();
        mlp_write_t<4>(b0_ + (size_t)m * 256, X, 0, wave, quad, l16, acc);
        mlp_write_t<4>(b0_ + (size_t)m * 256, X, 1, wave, quad, l16, acc2);
        __syncthreads();
    }

    // ---- main layers (K=256): weights in regs, 2 sub-tiles, 2 barriers/layer ----
    #pragma unroll 1
    for (int l = 0; l < 3; ++l) {
        short8 wr[4][8];
        load_w<256, 4>(w_bf + ((size_t)l * 64 + m) * 65536, wave, lane, wr);
        const float* bm = b_ + ((size_t)l * 64 + m) * 256;
        mfma_tile<256, 4>(wr, X, 0, quad, l16, acc);
        __syncthreads();
        mlp_write_t<4>(bm, X, 0, wave, quad, l16, acc);
        mfma_tile<256, 4>(wr, X, 1, quad, l16, acc);
        __syncthreads();
        mlp_write_t<4>(bm, X, 1, wave, quad, l16, acc);
    }
    __syncthreads();   // all w(1) writes visible before final layer reads tile 1

    // ---- final layer (K=256, 68 padded rows): direct global G write ----
    {
        short8 wfr[2][8];
        load_w<256, 2>(wf_bf + (size_t)m * 32768, wave, lane, wfr);
        const float* bm = bf_ + (size_t)m * 65;
        unsigned short* Gg = Gflat + (size_t)b0 * 4352 + m * 68;
        floatx4 acf[2][4];
        #pragma unroll
        for (int t = 0; t < 2; ++t) {
            mfma_tile<256, 2>(wfr, X, t, quad, l16, acf);
            #pragma unroll
            for (int i = 0; i < 2; ++i) {
                const int rb = wave * 32 + i * 16 + quad * 4;
                if (rb < 68) {
                    float c[4];
                    #pragma unroll
                    for (int rr = 0; rr < 4; ++rr)
                        c[rr] = (rb + rr < 65) ? bm[rb + rr] * NEG_LOG2E : 0.0f;
                    #pragma unroll
                    for (int j = 0; j < 4; ++j) {
                        const int cb = t * 64 + j * 16 + l16;
                        float r0 = fast_rcp(1.0f + fast_exp2(fmaf(acf[i][j][0], NEG_LOG2E, c[0])));
                        float r1 = fast_rcp(1.0f + fast_exp2(fmaf(acf[i][j][1], NEG_LOG2E, c[1])));
                        float r2 = fast_rcp(1.0f + fast_exp2(fmaf(acf[i][j][2], NEG_LOG2E, c[2])));
                        float r3 = fast_rcp(1.0f + fast_exp2(fmaf(acf[i][j][3], NEG_LOG2E, c[3])));
                        uint2 o = { pack_bf(r0, r1), pack_bf(r2, r3) };
                        *(uint2*)&Gg[(size_t)cb * 4352 + rb] = o;
                    }
                }
            }
        }
    }
}

// ---- contract helpers (R12) ----
__device__ __forceinline__ void stage_b64(
    const unsigned short* __restrict__ G, unsigned short* Bsb,
    int c0, int k0, int wave, int lrow, int spos)
{
    #pragma unroll
    for (int t = 0; t < 2; ++t) {
        const int row = wave * 16 + t * 8 + lrow;
        const int fc  = spos ^ (row & 7);
        load_lds16(G + (size_t)(c0 + row) * 4352 + k0 + fc * 8,
                   Bsb + (wave * 16 + t * 8) * 64);
    }
}

__device__ __forceinline__ void load_a(
    const unsigned short* __restrict__ Abase, int kt, short8 (&af)[8])
{
    #pragma unroll
    for (int i = 0; i < 4; ++i)
        #pragma unroll
        for (int kk = 0; kk < 2; ++kk)
            af[kk * 4 + i] = *(const short8*)(Abase + (size_t)(i * 136 + kt * 2 + kk) * 512);
}

__device__ __forceinline__ void comp_frag(
    const short8 (&af)[8], const unsigned short* Bsb,
    int wc, int quad, int l16, floatx4 (&acc)[4][2])
{
    #pragma unroll
    for (int kk = 0; kk < 2; ++kk) {
        short8 bfr[2];
        #pragma unroll
        for (int j = 0; j < 2; ++j) {
            const int cb = wc + j * 16 + l16;
            bfr[j] = *(const short8*)&Bsb[cb * 64 + (((kk * 4 + quad) ^ (cb & 7)) * 8)];
        }
        #pragma unroll
        for (int i = 0; i < 4; ++i)
            #pragma unroll
            for (int j = 0; j < 2; ++j)
                acc[i][j] = __builtin_amdgcn_mfma_f32_16x16x32_bf16(af[kk * 4 + i], bfr[j], acc[i][j], 0, 0, 0);
    }
}

// ---- contraction: FULL-K, 128n x 64b, A fragment-direct from L2 (R12) ----
// grid 512 = 32 n-tiles x 16 b-tiles, 2 blocks/CU (8 waves = 2/SIMD), 68 iters.
// R11's (256,1) was 1 wave/SIMD -> no latency hiding. Per CU-iter now:
// 128 MFMAs (621 cy) vs 32 ds_read_b128 (384 cy) -> MFMA-bound (floor 17.6us),
// vs R9/R10's 96 LDS reads (LDS-bound, 33us floor). A: 8 coalesced 1KB loads
// /iter/wave from the prep-fragmented XWf (L2-resident slice), double-buffered
// 1 K-tile ahead. B (G) staged in LDS, double-buffered. VGPR ~120 <= 128.
__global__ __launch_bounds__(256, 2)
void contract_gemm(const unsigned short* __restrict__ XWf,
                   const unsigned short* __restrict__ G,
                   float* __restrict__ out) {
    const int bid = blockIdx.x;
    const int xcd = bid & 7, slot = bid >> 3;           // 0..63
    const int r0 = ((xcd << 2) + (slot >> 4)) << 7;     // 32 n-tiles, 4/XCD
    const int c0 = (slot & 15) << 6;                    // 16 b-tiles of 64

    __shared__ unsigned short Bs[2][64 * 64];           // 2 x 8 KB

    const int tid = threadIdx.x;
    const int wave = tid >> 6, lane = tid & 63;
    const int quad = lane >> 4, l16 = lane & 15;
    const int wr = (wave & 1) * 64;                     // wave n-offset
    const int wc = (wave >> 1) * 32;                    // wave b-offset
    const int lrow = lane >> 3, spos = lane & 7;

    const unsigned short* Abase =
        XWf + ((size_t)(((r0 + wr) >> 4) * 136) * 64 + lane) * 8;

    floatx4 acc[4][2];
    #pragma unroll
    for (int i = 0; i < 4; ++i)
        #pragma unroll
        for (int j = 0; j < 2; ++j) acc[i][j] = (floatx4){0.f, 0.f, 0.f, 0.f};

    short8 afA[8], afB[8];

    // prologue: stage B k-tile 0, load A k-tile 0
    stage_b64(G, Bs[0], c0, 0, wave, lrow, spos);
    load_a(Abase, 0, afA);
    __syncthreads();

    for (int t = 0; t < 68; t += 2) {
        stage_b64(G, Bs[1], c0, (t + 1) * 64, wave, lrow, spos);
        load_a(Abase, t + 1, afB);
        comp_frag(afA, Bs[0], wc, quad, l16, acc);
        __syncthreads();
        if (t + 2 < 68) {
            stage_b64(G, Bs[0], c0, (t + 2) * 64, wave, lrow, spos);
            load_a(Abase, t + 2, afA);
        }
        comp_frag(afB, Bs[1], wc, quad, l16, acc);
        __syncthreads();
    }

    #pragma unroll
    for (int i = 0; i < 4; ++i) {
        const int rb = r0 + wr + i * 16 + quad * 4;
        #pragma unroll
        for (int rr = 0; rr < 4; ++rr)
            #pragma unroll
            for (int j = 0; j < 2; ++j) {
                const int col = c0 + wc + j * 16 + l16;
                out[(size_t)(rb + rr) * 1024 + col] = acc[i][j][rr];
            }
    }
}

extern "C" void kernel_launch(void* const* d_in, const int* in_sizes, int n_in,
                              void* d_out, int out_size, void* d_ws, size_t ws_size,
                              hipStream_t stream) {
    const float* u   = (const float*)d_in[0];
    const float* w0  = (const float*)d_in[1];
    const float* b0_ = (const float*)d_in[2];
    const float* w   = (const float*)d_in[3];
    const float* b   = (const float*)d_in[4];
    const float* wf  = (const float*)d_in[5];
    const float* bf_ = (const float*)d_in[6];
    const float* xi  = (const float*)d_in[7];
    float* out = (float*)d_out;

    unsigned short* w0_bf = (unsigned short*)d_ws;             // 1,048,576
    unsigned short* w_bf  = w0_bf + 1048576;                   // 12,582,912
    unsigned short* wf_bf = w_bf  + 12582912;                  // 2,097,152
    unsigned short* Gflat = wf_bf + 2097152;                   // 4,456,448 (1024 x 4352)
    unsigned short* XWf   = Gflat + 4456448;                   // 17,825,792 (256 nblk x 136 x 512)

    prep<<<12032, 256, 0, stream>>>(w0, w, wf, xi, w0_bf, w_bf, wf_bf, XWf);
    fused_mlp<<<512, 256, 0, stream>>>(u, w0_bf, b0_, w_bf, b, wf_bf, bf_, Gflat);
    contract_gemm<<<512, 256, 0, stream>>>(XWf, Gflat, out);
}

// Round 14
// 221.070 us; speedup vs baseline: 1.3351x; 1.1934x over previous
//
#include <hip/hip_runtime.h>
#include <math.h>

typedef __attribute__((ext_vector_type(8))) short short8;
typedef __attribute__((ext_vector_type(4))) float floatx4;

__device__ __forceinline__ void load_lds16(const void* g, void* l) {
    __builtin_amdgcn_global_load_lds((const __attribute__((address_space(1))) void*)g,
                                     (__attribute__((address_space(3))) void*)l,
                                     16, 0, 0);
}

__device__ __forceinline__ unsigned short f2bf(float x) {
    union { float f; unsigned int u; } v; v.f = x;
    unsigned int r = v.u + 0x7fffu + ((v.u >> 16) & 1u);
    return (unsigned short)(r >> 16);
}

// pack two fp32 -> two bf16 (round-half-up) in one v_perm_b32
__device__ __forceinline__ unsigned int pack_bf(float f0, float f1) {
    union { float f; unsigned int u; } a, b;
    a.f = f0; b.f = f1;
    return __builtin_amdgcn_perm(b.u + 0x8000u, a.u + 0x8000u, 0x07060302u);
}

__device__ __forceinline__ float fast_exp2(float x) {
#if __has_builtin(__builtin_amdgcn_exp2f)
    return __builtin_amdgcn_exp2f(x);
#else
    return __expf(x * 0.69314718056f);
#endif
}

__device__ __forceinline__ float fast_rcp(float x) {
#if __has_builtin(__builtin_amdgcn_rcpf)
    return __builtin_amdgcn_rcpf(x);
#else
    return 1.0f / x;
#endif
}

#define NEG_LOG2E (-1.4426950408889634f)

// ---- prep: weights -> bf16 in MFMA-fragment order + Toeplitz XW build (R9) ----
// blocks: [0,512) w0 | [512,6656) w | [6656,7680) wf-pad | [7680,11776) XW rows
__global__ void prep(const float* __restrict__ w0, const float* __restrict__ w,
                     const float* __restrict__ wf, const float* __restrict__ xi,
                     unsigned short* __restrict__ w0d, unsigned short* __restrict__ wd,
                     unsigned short* __restrict__ wfd, unsigned int* __restrict__ xw) {
    const int bid = blockIdx.x;
    if (bid < 6656) {
        const bool is0 = bid < 512;
        const int c = (is0 ? bid : bid - 512) * 256 + threadIdx.x;
        const int cpm = is0 ? 2048 : 8192;
        const int Kk  = is0 ? 2 : 8;
        const int K   = Kk * 32;
        const int mm  = c / cpm;
        const int cm  = c - mm * cpm;
        const int rblk = cm / (Kk * 64);
        const int rem  = cm - rblk * (Kk * 64);
        const int kk   = rem >> 6;
        const int lane = rem & 63;
        const int r  = rblk * 16 + (lane & 15);
        const int k0 = kk * 32 + (lane >> 4) * 8;
        const float* srcp = (is0 ? w0 : w) + ((size_t)mm * 256 + r) * K + k0;
        unsigned short* dstp = (is0 ? w0d : wd) + (size_t)c * 8;
        float4 a = *(const float4*)srcp;
        float4 b = *(const float4*)(srcp + 4);
        short8 o = { (short)f2bf(a.x), (short)f2bf(a.y), (short)f2bf(a.z), (short)f2bf(a.w),
                     (short)f2bf(b.x), (short)f2bf(b.y), (short)f2bf(b.z), (short)f2bf(b.w) };
        *(short8*)dstp = o;
    } else if (bid < 7680) {
        const int c = (bid - 6656) * 256 + threadIdx.x;
        const int m  = c >> 12;
        const int cm = c & 4095;
        const int rblk = cm >> 9;
        const int rem  = cm & 511;
        const int kk   = rem >> 6;
        const int lane = rem & 63;
        const int r  = rblk * 16 + (lane & 15);
        const int k0 = kk * 32 + (lane >> 4) * 8;
        short8 o = {0,0,0,0,0,0,0,0};
        if (r < 65) {
            const float* srcp = wf + ((size_t)m * 65 + r) * 256 + k0;
            float4 a = *(const float4*)srcp;
            float4 b = *(const float4*)(srcp + 4);
            o = (short8){ (short)f2bf(a.x), (short)f2bf(a.y), (short)f2bf(a.z), (short)f2bf(a.w),
                          (short)f2bf(b.x), (short)f2bf(b.y), (short)f2bf(b.z), (short)f2bf(b.w) };
        }
        *(short8*)(wfd + (size_t)c * 8) = o;
    } else {
        const int n = bid - 7680;
        #pragma unroll
        for (int t = 0; t < 9; ++t) {
            const int idx = t * 256 + threadIdx.x;
            if (idx < 2176) {
                const int m = idx / 34;
                const int pos = idx - m * 34;
                const int j0 = pos * 2;
                const float* xim = xi + (size_t)m * 4160 + n;
                const float v0 = (j0 < 65) ? xim[j0] : 0.0f;
                const float v1 = (j0 + 1 < 65) ? xim[j0 + 1] : 0.0f;
                xw[(size_t)n * 2176 + idx] =
                    (unsigned int)f2bf(v0) | ((unsigned int)f2bf(v1) << 16);
            }
        }
    }
}

// ---- weight fragments -> registers, once per layer ----
template<int K, int I>
__device__ __forceinline__ void load_w(
    const unsigned short* __restrict__ Wt, int wave, int lane, short8 (&w)[I][K / 32])
{
    constexpr int Kk = K / 32;
    const unsigned short* wb = Wt + ((size_t)(wave * I * Kk) * 64 + lane) * 8;
    #pragma unroll
    for (int i = 0; i < I; ++i)
        #pragma unroll
        for (int kk = 0; kk < Kk; ++kk)
            w[i][kk] = *(const short8*)(wb + (size_t)(i * Kk + kk) * 512);
}

// ---- MFMA sweep over one 64-col sub-tile t, weights from registers ----
// X layout: X[b][k] at b*K + ((k/8) ^ (b&7))*8 + (k&7)   (shorts)
template<int K, int I>
__device__ __forceinline__ void mfma_tile(
    const short8 (&w)[I][K / 32], const unsigned short* src, int t,
    int quad, int l16, floatx4 (&acc)[I][4])
{
    constexpr int Kk = K / 32;
    #pragma unroll
    for (int i = 0; i < I; ++i)
        #pragma unroll
        for (int j = 0; j < 4; ++j) acc[i][j] = (floatx4){0.f, 0.f, 0.f, 0.f};
    #pragma unroll
    for (int kk = 0; kk < Kk; ++kk) {
        short8 bf[4];
        #pragma unroll
        for (int j = 0; j < 4; ++j) {
            const int cb = t * 64 + j * 16 + l16;
            bf[j] = *(const short8*)&src[cb * K + (((kk * 4 + quad) ^ (cb & 7)) * 8)];
        }
        #pragma unroll
        for (int i = 0; i < I; ++i)
            #pragma unroll
            for (int j = 0; j < 4; ++j)
                acc[i][j] = __builtin_amdgcn_mfma_f32_16x16x32_bf16(w[i][kk], bf[j], acc[i][j], 0, 0, 0);
    }
}

// epilogue for sub-tile t: fused bias+sigmoid, perm pack, in-place K_out=256 layout
template<int I>
__device__ __forceinline__ void mlp_write_t(
    const float* __restrict__ bm, unsigned short* dst, int t,
    int wave, int quad, int l16, floatx4 (&acc)[I][4])
{
    const int rbw = wave * (I * 16);
    #pragma unroll
    for (int i = 0; i < I; ++i) {
        const int rb = rbw + i * 16 + quad * 4;
        float c0 = bm[rb]     * NEG_LOG2E;
        float c1 = bm[rb + 1] * NEG_LOG2E;
        float c2 = bm[rb + 2] * NEG_LOG2E;
        float c3 = bm[rb + 3] * NEG_LOG2E;
        #pragma unroll
        for (int j = 0; j < 4; ++j) {
            const int cb = t * 64 + j * 16 + l16;
            float r0 = fast_rcp(1.0f + fast_exp2(fmaf(acc[i][j][0], NEG_LOG2E, c0)));
            float r1 = fast_rcp(1.0f + fast_exp2(fmaf(acc[i][j][1], NEG_LOG2E, c1)));
            float r2 = fast_rcp(1.0f + fast_exp2(fmaf(acc[i][j][2], NEG_LOG2E, c2)));
            float r3 = fast_rcp(1.0f + fast_exp2(fmaf(acc[i][j][3], NEG_LOG2E, c3)));
            uint2 o = { pack_bf(r0, r1), pack_bf(r2, r3) };
            *(uint2*)&dst[cb * 256 + (((rb >> 3) ^ (cb & 7)) * 8) + (rb & 7)] = o;
        }
    }
}

// ---- fused MLP, weight-register-resident (R5 version — best measured, 49.8 us) ----
__global__ __launch_bounds__(256, 2)
void fused_mlp(const float* __restrict__ u,
               const unsigned short* __restrict__ w0_bf, const float* __restrict__ b0_,
               const unsigned short* __restrict__ w_bf,  const float* __restrict__ b_,
               const unsigned short* __restrict__ wf_bf, const float* __restrict__ bf_,
               unsigned short* __restrict__ Gflat) {
    __shared__ unsigned short X[128 * 256];   // 64 KB

    const int bid = blockIdx.x;
    const int xcd = bid & 7, slot = bid >> 3;           // slot 0..63
    const int m  = (xcd << 3) + (slot >> 3);            // 8 m per XCD
    const int b0 = (slot & 7) << 7;                     // 8 batch-tiles of 128
    const int tid = threadIdx.x, wave = tid >> 6, lane = tid & 63;
    const int quad = lane >> 4, l16 = lane & 15;

    // stage u (fp32) -> X (bf16, K=64 layout), perm-packed
    {
        const int b = tid >> 1, hk = tid & 1;
        const float* up = u + (size_t)(b0 + b) * 64 + hk * 32;
        #pragma unroll
        for (int c = 0; c < 4; ++c) {
            float4 v0 = *(const float4*)(up + c * 8);
            float4 v1 = *(const float4*)(up + c * 8 + 4);
            uint4 p = { pack_bf(v0.x, v0.y), pack_bf(v0.z, v0.w),
                        pack_bf(v1.x, v1.y), pack_bf(v1.z, v1.w) };
            *(uint4*)&X[b * 64 + (((hk * 4 + c) ^ (b & 7)) * 8)] = p;
        }
    }
    __syncthreads();

    floatx4 acc[4][4];

    // ---- layer 0 (K=64): both sub-tiles computed before any write ----
    {
        short8 w0r[4][2];
        load_w<64, 4>(w0_bf + (size_t)m * 16384, wave, lane, w0r);
        floatx4 acc2[4][4];
        mfma_tile<64, 4>(w0r, X, 0, quad, l16, acc);
        mfma_tile<64, 4>(w0r, X, 1, quad, l16, acc2);
        __syncthreads();
        mlp_write_t<4>(b0_ + (size_t)m * 256, X, 0, wave, quad, l16, acc);
        mlp_write_t<4>(b0_ + (size_t)m * 256, X, 1, wave, quad, l16, acc2);
        __syncthreads();
    }

    // ---- main layers (K=256): weights in regs, 2 sub-tiles, 2 barriers/layer ----
    #pragma unroll 1
    for (int l = 0; l < 3; ++l) {
        short8 wr[4][8];
        load_w<256, 4>(w_bf + ((size_t)l * 64 + m) * 65536, wave, lane, wr);
        const float* bm = b_ + ((size_t)l * 64 + m) * 256;
        mfma_tile<256, 4>(wr, X, 0, quad, l16, acc);
        __syncthreads();
        mlp_write_t<4>(bm, X, 0, wave, quad, l16, acc);
        mfma_tile<256, 4>(wr, X, 1, quad, l16, acc);
        __syncthreads();
        mlp_write_t<4>(bm, X, 1, wave, quad, l16, acc);
    }
    __syncthreads();   // all w(1) writes visible before final layer reads tile 1

    // ---- final layer (K=256, 68 padded rows): direct global G write ----
    {
        short8 wfr[2][8];
        load_w<256, 2>(wf_bf + (size_t)m * 32768, wave, lane, wfr);
        const float* bm = bf_ + (size_t)m * 65;
        unsigned short* Gg = Gflat + (size_t)b0 * 4352 + m * 68;
        floatx4 acf[2][4];
        #pragma unroll
        for (int t = 0; t < 2; ++t) {
            mfma_tile<256, 2>(wfr, X, t, quad, l16, acf);
            #pragma unroll
            for (int i = 0; i < 2; ++i) {
                const int rb = wave * 32 + i * 16 + quad * 4;
                if (rb < 68) {
                    float c[4];
                    #pragma unroll
                    for (int rr = 0; rr < 4; ++rr)
                        c[rr] = (rb + rr < 65) ? bm[rb + rr] * NEG_LOG2E : 0.0f;
                    #pragma unroll
                    for (int j = 0; j < 4; ++j) {
                        const int cb = t * 64 + j * 16 + l16;
                        float r0 = fast_rcp(1.0f + fast_exp2(fmaf(acf[i][j][0], NEG_LOG2E, c[0])));
                        float r1 = fast_rcp(1.0f + fast_exp2(fmaf(acf[i][j][1], NEG_LOG2E, c[1])));
                        float r2 = fast_rcp(1.0f + fast_exp2(fmaf(acf[i][j][2], NEG_LOG2E, c[2])));
                        float r3 = fast_rcp(1.0f + fast_exp2(fmaf(acf[i][j][3], NEG_LOG2E, c[3])));
                        uint2 o = { pack_bf(r0, r1), pack_bf(r2, r3) };
                        *(uint2*)&Gg[(size_t)cb * 4352 + rb] = o;
                    }
                }
            }
        }
    }
}

// ---- contract staging/compute helpers (R9 tile shape) ----
__device__ __forceinline__ void stage_cb(
    const unsigned short* __restrict__ XW, const unsigned short* __restrict__ G,
    unsigned short* Asb, unsigned short* Bsb,
    int r0, int c0, int k0, int wave, int lrow, int spos)
{
    #pragma unroll
    for (int t = 0; t < 4; ++t) {
        const int row = wave * 32 + t * 8 + lrow;
        const int fc  = spos ^ (row & 7);
        load_lds16(XW + (size_t)(r0 + row) * 4352 + k0 + fc * 8,
                   Asb + (wave * 32 + t * 8) * 64);
    }
    #pragma unroll
    for (int t = 0; t < 2; ++t) {
        const int row = wave * 16 + t * 8 + lrow;
        const int fc  = spos ^ (row & 7);
        load_lds16(G + (size_t)(c0 + row) * 4352 + k0 + fc * 8,
                   Bsb + (wave * 16 + t * 8) * 64);
    }
}

__device__ __forceinline__ void comp_cb(
    const unsigned short* Asb, const unsigned short* Bsb,
    int wr, int wc, int quad, int l16, floatx4 (&acc)[4][2])
{
    #pragma unroll
    for (int kk = 0; kk < 2; ++kk) {
        short8 af[4], bfr[2];
        #pragma unroll
        for (int i = 0; i < 4; ++i) {
            const int ra = wr + i * 16 + l16;
            af[i] = *(const short8*)&Asb[ra * 64 + (((kk * 4 + quad) ^ (ra & 7)) * 8)];
        }
        #pragma unroll
        for (int j = 0; j < 2; ++j) {
            const int cb = wc + j * 16 + l16;
            bfr[j] = *(const short8*)&Bsb[cb * 64 + (((kk * 4 + quad) ^ (cb & 7)) * 8)];
        }
        #pragma unroll
        for (int i = 0; i < 4; ++i)
            #pragma unroll
            for (int j = 0; j < 2; ++j)
                acc[i][j] = __builtin_amdgcn_mfma_f32_16x16x32_bf16(af[i], bfr[j], acc[i][j], 0, 0, 0);
    }
}

// ---- contraction: FULL-K, 128n x 64b, counted-vmcnt pipeline (R14) ----
// grid 512 = 32 n x 16 b, 2 blocks/CU, 68 K-iters, fp32 direct out.
// R10's dbuf failed because __syncthreads drains vmcnt(0) at every barrier
// (the m97-ceiling mechanism). T4 fix: raw s_barrier + counted vmcnt(6) —
// only tile t+1's 6 loads must complete; tile t+2's 6 stay in flight across
// the barrier, issued one full compute phase (~1150cy) before needed.
// Hazard walk: bar1 = all waves done READING buf p before it is re-staged;
// each wave's vmcnt(6) before bar2 = its tile-(t+1) loads complete -> after
// bar2 all of buf p^1 is written; tail iterations use vmcnt(0).
__global__ __launch_bounds__(256, 2)
void contract_gemm(const unsigned short* __restrict__ XW,
                   const unsigned short* __restrict__ G,
                   float* __restrict__ out) {
    const int bid = blockIdx.x;
    const int xcd = bid & 7, slot = bid >> 3;           // 0..63
    const int r0 = ((xcd << 2) + (slot >> 4)) << 7;     // 32 n-tiles, 4/XCD
    const int c0 = (slot & 15) << 6;                    // 16 b-tiles of 64

    __shared__ unsigned short As[2][128 * 64];          // 2 x 16 KB
    __shared__ unsigned short Bs[2][64 * 64];           // 2 x 8 KB

    const int tid = threadIdx.x;
    const int wave = tid >> 6, lane = tid & 63;
    const int quad = lane >> 4, l16 = lane & 15;
    const int wr = (wave & 1) * 64;                     // wave n-offset
    const int wc = (wave >> 1) * 32;                    // wave b-offset
    const int lrow = lane >> 3, spos = lane & 7;

    floatx4 acc[4][2];
    #pragma unroll
    for (int i = 0; i < 4; ++i)
        #pragma unroll
        for (int j = 0; j < 2; ++j) acc[i][j] = (floatx4){0.f, 0.f, 0.f, 0.f};

    // prologue: stage tiles 0 and 1; wait only tile-0's 6 loads (6 remain in flight)
    stage_cb(XW, G, As[0], Bs[0], r0, c0, 0, wave, lrow, spos);
    stage_cb(XW, G, As[1], Bs[1], r0, c0, 64, wave, lrow, spos);
    asm volatile("s_waitcnt vmcnt(6)" ::: "memory");
    __builtin_amdgcn_s_barrier();

    for (int t = 0; t < 68; t += 2) {
        // ---- tile t (buf 0) ----
        comp_cb(As[0], Bs[0], wr, wc, quad, l16, acc);
        __builtin_amdgcn_s_barrier();                   // readers of buf0 done
        if (t + 2 < 68) {
            stage_cb(XW, G, As[0], Bs[0], r0, c0, (t + 2) * 64, wave, lrow, spos);
            asm volatile("s_waitcnt vmcnt(6)" ::: "memory");   // tile t+1 ready
        } else {
            asm volatile("s_waitcnt vmcnt(0)" ::: "memory");
        }
        __builtin_amdgcn_s_barrier();                   // buf1 (tile t+1) readable
        // ---- tile t+1 (buf 1) ----
        comp_cb(As[1], Bs[1], wr, wc, quad, l16, acc);
        __builtin_amdgcn_s_barrier();                   // readers of buf1 done
        if (t + 3 < 68) {
            stage_cb(XW, G, As[1], Bs[1], r0, c0, (t + 3) * 64, wave, lrow, spos);
            asm volatile("s_waitcnt vmcnt(6)" ::: "memory");   // tile t+2 ready
        } else {
            asm volatile("s_waitcnt vmcnt(0)" ::: "memory");
        }
        __builtin_amdgcn_s_barrier();                   // buf0 (tile t+2) readable
    }

    #pragma unroll
    for (int i = 0; i < 4; ++i) {
        const int rb = r0 + wr + i * 16 + quad * 4;
        #pragma unroll
        for (int rr = 0; rr < 4; ++rr)
            #pragma unroll
            for (int j = 0; j < 2; ++j) {
                const int col = c0 + wc + j * 16 + l16;
                out[(size_t)(rb + rr) * 1024 + col] = acc[i][j][rr];
            }
    }
}

extern "C" void kernel_launch(void* const* d_in, const int* in_sizes, int n_in,
                              void* d_out, int out_size, void* d_ws, size_t ws_size,
                              hipStream_t stream) {
    const float* u   = (const float*)d_in[0];
    const float* w0  = (const float*)d_in[1];
    const float* b0_ = (const float*)d_in[2];
    const float* w   = (const float*)d_in[3];
    const float* b   = (const float*)d_in[4];
    const float* wf  = (const float*)d_in[5];
    const float* bf_ = (const float*)d_in[6];
    const float* xi  = (const float*)d_in[7];
    float* out = (float*)d_out;

    unsigned short* w0_bf = (unsigned short*)d_ws;             // 1,048,576
    unsigned short* w_bf  = w0_bf + 1048576;                   // 12,582,912
    unsigned short* wf_bf = w_bf  + 12582912;                  // 2,097,152
    unsigned short* Gflat = wf_bf + 2097152;                   // 4,456,448 (1024 x 4352)
    unsigned short* XW    = Gflat + 4456448;                   // 17,825,792 (4096 x 4352)

    prep<<<11776, 256, 0, stream>>>(w0, w, wf, xi, w0_bf, w_bf, wf_bf, (unsigned int*)XW);
    fused_mlp<<<512, 256, 0, stream>>>(u, w0_bf, b0_, w_bf, b, wf_bf, bf_, Gflat);
    contract_gemm<<<512, 256, 0, stream>>>(XW, Gflat, out);
}